// Round 16
// baseline (135.060 us; speedup 1.0000x reference)
//
#include <hip/hip_runtime.h>

typedef float f32x4 __attribute__((ext_vector_type(4)));
typedef short s16x8 __attribute__((ext_vector_type(8)));

constexpr int B  = 2;
constexpr int S  = 1025;
constexpr int D  = 768;
constexpr int DD = D * D;
constexpr int H  = 12;
constexpr int NM = 4;
constexpr int ROWS = B * S;              // 2050
constexpr int BSD  = B * S * D;          // 1,574,400
constexpr int KPAD = 1088;               // padded key dim for mask table
constexpr int NHB  = B * H;              // 24
constexpr int NQT  = 65;                 // q-tiles of 16
constexpr int NKT  = 17;                 // key-tiles of 64
constexpr int NV5  = 5;                  // softmax variants (base + 4 masks)
constexpr int NATT = NHB * NQT;          // 1560 attention blocks (= 8 x 195)
constexpr int NCPY = 512;                // copy blocks appended to attn grid
constexpr int OUT_NEWH_OFF = BSD;
constexpr int OUT_IDX_OFF  = BSD + NM * BSD;
constexpr int OUT_NEWX_OFF = OUT_IDX_OFF + B * NM;

// fold 1/sqrt(64) * log2(e) into Q so attention uses raw v_exp_f32 (2^x)
#define QSCALE 0.18033688011112042f

// fragment array sizes (u16 elements)
constexpr size_t QF_SZ = (size_t)NHB * NQT * 2 * 512;        // 1,597,440
constexpr size_t KF_SZ = (size_t)NHB * NKT * 4 * 2 * 512;    // 1,671,168
constexpr size_t VF_SZ = KF_SZ;

__device__ __forceinline__ unsigned short f2bf(float f) {
    unsigned u = __builtin_bit_cast(unsigned, f);
    u += 0x7FFF + ((u >> 16) & 1);          // RTNE
    return (unsigned short)(u >> 16);
}

__device__ __forceinline__ void gll16(const void* g, void* l) {
    __builtin_amdgcn_global_load_lds(
        (const __attribute__((address_space(1))) void*)g,
        (__attribute__((address_space(3))) void*)l, 16, 0, 0);
}

// ---------------------------------------------------------------------------
// Kernel 0: convert x, Wq/Wk/Wv to bf16; build 5-variant bf16 mask bitmask
// table; zero the PAD fragment tiles of Qf/Kf/Vf.
// xb/Wb live in the out_newx region of d_out (overwritten by the copy blocks
// of the attention launch, which runs after qkv consumed xb/Wb).
// ---------------------------------------------------------------------------
__global__ __launch_bounds__(256) void conv_kernel(
    const float* __restrict__ x, const float* __restrict__ Wq,
    const float* __restrict__ Wk, const float* __restrict__ Wv,
    const int* __restrict__ masks,
    unsigned short* __restrict__ xb, unsigned short* __restrict__ Wb,
    unsigned short* __restrict__ Mmb,
    unsigned short* __restrict__ Qf, unsigned short* __restrict__ Kf,
    unsigned short* __restrict__ Vf)
{
    constexpr int NX8 = BSD / 8;        // 196800
    constexpr int NW8 = DD / 8;         // 73728
    constexpr int TOT = NX8 + 3 * NW8;  // 417984
    const int stride = gridDim.x * 256;
    const int tid = blockIdx.x * 256 + threadIdx.x;
    for (int c = tid; c < TOT; c += stride) {
        const float* src;
        unsigned short* dst;
        if (c < NX8) { src = x + (size_t)c * 8; dst = xb + (size_t)c * 8; }
        else {
            const int cc = c - NX8;
            const int mt = cc / NW8;
            const int rr = cc - mt * NW8;
            src = ((mt == 0) ? Wq : (mt == 1) ? Wk : Wv) + (size_t)rr * 8;
            dst = Wb + (size_t)mt * DD + (size_t)rr * 8;
        }
        const float4 a = *(const float4*)src;
        const float4 b2 = *(const float4*)(src + 4);
        s16x8 v;
        v[0] = (short)f2bf(a.x);  v[1] = (short)f2bf(a.y);
        v[2] = (short)f2bf(a.z);  v[3] = (short)f2bf(a.w);
        v[4] = (short)f2bf(b2.x); v[5] = (short)f2bf(b2.y);
        v[6] = (short)f2bf(b2.z); v[7] = (short)f2bf(b2.w);
        *(s16x8*)dst = v;
    }
    // mask bitmask table: Mmb[b][vv][KPAD]; vv=0 keeps all real keys
    if (tid < B * NV5 * KPAD) {            // 10880
        const int k    = tid % KPAD;
        const int rest = tid / KPAD;
        const int vv   = rest % NV5;
        const int bb   = rest / NV5;
        unsigned short m;
        if (vv == 0) m = (k < S) ? 0xFFFFu : 0u;
        else m = (k >= 1 && k < S &&
                  masks[(size_t)(bb * NM + vv - 1) * (S - 1) + k - 1]) ? 0xFFFFu : 0u;
        Mmb[tid] = m;
    }
    // zero pad fragment tiles (qkv_mfma writes the valid entries afterwards)
    constexpr int KZ = NHB * 8 * 512;      // 98304 (last key tile: rows 1024..1087)
    for (int i = tid; i < KZ; i += stride) {
        const int hb = i >> 12, off = i & 4095;
        Kf[(((size_t)(hb * NKT + NKT - 1)) << 12) + off] = 0;
        Vf[(((size_t)(hb * NKT + NKT - 1)) << 12) + off] = 0;
    }
    constexpr int QZ = NHB * 2 * 512;      // 24576 (last q tile: rows 1024..1039)
    for (int i = tid; i < QZ; i += stride) {
        const int hb = i >> 10, off = i & 1023;
        Qf[(((size_t)(hb * NQT + NQT - 1) * 2) << 9) + off] = 0;
    }
}

// ---------------------------------------------------------------------------
// Kernel 1: QKV projection as ONE 128x128-tile bf16 MFMA GEMM over the
// concatenated weight matrix [2304][768] (tiles 0-5 = Q, 6-11 = K, 12-17 = V).
// 256 thr = 4 waves in 2x2, each wave a 64x64 quadrant, BK=64, double-
// buffered gll staging. Epilogue scatters to MFMA FRAGMENT ORDER:
//   Qf[hb][qt][kh][lane][8]  elem = Q[qt*16+(l&15)][(l>>4)*8+kh*32+e]*QSCALE
//   Kf[hb][tile][kt][kh][lane][8] = K[tile*64+kt*16+(l&15)][(l>>4)*8+kh*32+e]
//   Vf[hb][tile][dt][kh][lane][8] = V[tile*64+(l>>4)*8+kh*32+e][dt*16+(l&15)]
// ---------------------------------------------------------------------------
__global__ __launch_bounds__(256, 2) void qkv_mfma_kernel(
    const unsigned short* __restrict__ xb, const unsigned short* __restrict__ Wb,
    const float* __restrict__ bq, const float* __restrict__ bk,
    const float* __restrict__ bv,
    unsigned short* __restrict__ Qf, unsigned short* __restrict__ Kf,
    unsigned short* __restrict__ Vf)
{
    __shared__ __align__(16) unsigned short Xs[2][128 * 64];
    __shared__ __align__(16) unsigned short Wl[2][128 * 64];

    const int t = threadIdx.x;
    const int row0 = blockIdx.x * 128;
    const int cy = blockIdx.y;           // 0..17
    const int mt = cy / 6;
    const int col0 = (cy % 6) * 128;     // within-matrix column base
    const float* bias = (mt == 0) ? bq : (mt == 1) ? bk : bv;
    const unsigned short* Wsrc = Wb + (size_t)mt * DD;

    const int w = t >> 6, l = t & 63, lq = l & 15, grp = l >> 4;
    const int wr = w >> 1, wc = w & 1;   // wave quadrant (2x2)

    auto stage = [&](int buf, int k0) {
        #pragma unroll
        for (int i = 0; i < 4; ++i) {
            const int slot = i * 256 + t;           // 0..1023 chunks
            const int r = slot >> 3, cl = slot & 7;
            const int cg = cl ^ (r & 7);
            int row = row0 + r; if (row > ROWS - 1) row = ROWS - 1;
            gll16(xb + (size_t)row * D + k0 + cg * 8, &Xs[buf][slot * 8]);
            gll16(Wsrc + (size_t)(col0 + r) * D + k0 + cg * 8, &Wl[buf][slot * 8]);
        }
    };

    f32x4 acc[4][4] = {};
    stage(0, 0);

    for (int ks = 0; ks < 12; ++ks) {
        const int cur = ks & 1;
        __syncthreads();
        if (ks + 1 < 12) stage(cur ^ 1, (ks + 1) * 64);

        s16x8 a[4][2], bf[4][2];
        #pragma unroll
        for (int i = 0; i < 4; ++i) {
            const int xr = wr * 64 + i * 16 + lq;
            #pragma unroll
            for (int kh = 0; kh < 2; ++kh)
                a[i][kh] = *(const s16x8*)&Xs[cur][xr * 64 + (((kh * 4 + grp) ^ (xr & 7)) * 8)];
        }
        #pragma unroll
        for (int j = 0; j < 4; ++j) {
            const int wrow = wc * 64 + j * 16 + lq;
            #pragma unroll
            for (int kh = 0; kh < 2; ++kh)
                bf[j][kh] = *(const s16x8*)&Wl[cur][wrow * 64 + (((kh * 4 + grp) ^ (wrow & 7)) * 8)];
        }
        #pragma unroll
        for (int i = 0; i < 4; ++i)
            #pragma unroll
            for (int j = 0; j < 4; ++j) {
                acc[i][j] = __builtin_amdgcn_mfma_f32_16x16x32_bf16(a[i][0], bf[j][0], acc[i][j], 0, 0, 0);
                acc[i][j] = __builtin_amdgcn_mfma_f32_16x16x32_bf16(a[i][1], bf[j][1], acc[i][j], 0, 0, 0);
            }
    }

    // epilogue: bias add + fragment-order scatter (bf16)
    #pragma unroll
    for (int j = 0; j < 4; ++j) {
        const int col = col0 + wc * 64 + j * 16 + lq;   // 0..767 within matrix
        const float bv_ = bias[col];
        #pragma unroll
        for (int i = 0; i < 4; ++i) {
            #pragma unroll
            for (int r = 0; r < 4; ++r) {
                const int row = row0 + wr * 64 + i * 16 + grp * 4 + r;
                if (row >= ROWS) continue;
                const float raw = acc[i][j][r] + bv_;
                const int bb = (row >= S) ? 1 : 0;
                const int s  = row - bb * S;
                const int hb2 = bb * H + (col >> 6);
                const int d   = col & 63;
                if (mt == 0) {
                    const size_t idx = (((size_t)(hb2 * NQT + (s >> 4)) * 2 + (d >> 5)) << 9)
                                     + (((((d >> 3) & 3) << 4) + (s & 15)) << 3) + (d & 7);
                    Qf[idx] = f2bf(raw * QSCALE);
                } else if (mt == 1) {
                    const size_t idx = ((((size_t)(hb2 * NKT + (s >> 6)) * 4 + ((s >> 4) & 3)) * 2 + (d >> 5)) << 9)
                                     + (((((d >> 3) & 3) << 4) + (s & 15)) << 3) + (d & 7);
                    Kf[idx] = f2bf(raw);
                } else {
                    const int kk = s & 63;
                    const size_t idx = ((((size_t)(hb2 * NKT + (s >> 6)) * 4 + (d >> 4)) * 2 + (kk >> 5)) << 9)
                                     + (((((kk >> 3) & 3) << 4) + (d & 15)) << 3) + (kk & 7);
                    Vf[idx] = f2bf(raw);
                }
            }
        }
    }
}

// ---------------------------------------------------------------------------
// Kernel 2: d-split producer/consumer MFMA attention + fused new_x copy.
// Attn blocks (< NATT): 384 thr = 6 waves, ONE 16-q tile of one (b,h):
//   wave 0 (producer): K from LDS (double-buffered gll staging, K ONLY) ->
//     QK^T (8 MFMA) -> exp/cvt_pk -> P(it) to LDS.
//   waves 1..4 (d-consumers): wave w owns d-tile dt=w-1; reads its OWN V
//     slice direct from global (2 b128, prefetch-carried) + P(it-1) (2 b128)
//     and computes ALL 5 variants' PV on that d-tile (10 MFMA). V is read
//     ONCE in total (was 5x) — cuts block-phase LDS reads 58 -> 18 b128.
//   wave 5 (sum): reads P(it-1), 10 ones-MFMA -> 5 per-variant sums; shares
//     them via a tiny LDS table at the end.
// Copy blocks (>= NATT): new_x broadcast copy + img_idx.
// ---------------------------------------------------------------------------
__global__ __launch_bounds__(384) void attn_mfma_kernel(
    const unsigned short* __restrict__ Qf, const unsigned short* __restrict__ Kf,
    const unsigned short* __restrict__ Vf, const unsigned short* __restrict__ Mmb,
    const float* __restrict__ x,
    float* __restrict__ out_h, float* __restrict__ out_newh,
    float* __restrict__ out_newx, float* __restrict__ out_idx)
{
    if (blockIdx.x >= NATT) {
        // ---- fused tail: new_x broadcast copy + img_idx ----
        const int cb = blockIdx.x - NATT;
        const int SLAB4  = S * D / 4;
        const int TOTAL4 = B * NM * SLAB4;
        const float4* x4 = (const float4*)x;
        float4* o4 = (float4*)out_newx;
        for (int f = cb * 384 + threadIdx.x; f < TOTAL4; f += NCPY * 384) {
            const int bm  = f / SLAB4;
            const int rem = f - bm * SLAB4;
            o4[f] = x4[(bm >> 2) * SLAB4 + rem];
        }
        if (cb == 0 && threadIdx.x < B * NM)
            out_idx[threadIdx.x] = (float)(threadIdx.x >> 2);
        return;
    }

    __shared__ __align__(16) unsigned short Kl[2][4096];   // K only, 16KB
    __shared__ __align__(16) unsigned short Pb2[2][1024];  // shared P, 4KB
    __shared__ float Ssum[NV5][16];                        // 320B

    const int orig = blockIdx.x;
    const int wgid = (orig & 7) * 195 + (orig >> 3);   // 1560 = 8 x 195
    const int hb = wgid / NQT;           // 0..23
    const int qt = wgid - hb * NQT;      // 0..64
    const int b  = hb / H, hh = hb - b * H;
    const int q0 = qt * 16;

    const int t = threadIdx.x;
    const int w = t >> 6, l = t & 63;
    const int lq = l & 15, grp = l >> 4;

    const unsigned short* kfT = Kf + (((size_t)(hb * NKT)) << 12);

    // all threads cooperatively stage K tile -> LDS buf (flat, lane-linear)
    auto stage = [&](int buf, int tile) {
        const unsigned short* ks = kfT + ((size_t)tile << 12);
        #pragma unroll
        for (int i = 0; i < 2; ++i) {
            const int s = t + i * 384;
            if (s < 512) gll16(ks + s * 8, &Kl[buf][s * 8]);
        }
    };

    stage(0, 0);

    if (w == 0) {
        // ================= producer: QK + exp + P =================
        s16x8 qf0, qf1;
        {
            const unsigned short* p = Qf + (((size_t)(hb * NQT + qt) * 2) << 9) + (l << 3);
            qf0 = *(const s16x8*)p;
            qf1 = *(const s16x8*)(p + 512);
        }
        #pragma unroll 1
        for (int it = 0; it < NKT; ++it) {
            const int cur = it & 1;
            __syncthreads();
            if (it + 1 < NKT) stage(cur ^ 1, it + 1);

            f32x4 qk[4] = {};
            __builtin_amdgcn_s_setprio(1);
            #pragma unroll
            for (int kt = 0; kt < 4; ++kt) {
                s16x8 k0v = *(const s16x8*)&Kl[cur][((kt * 2 + 0) << 9) + l * 8];
                s16x8 k1v = *(const s16x8*)&Kl[cur][((kt * 2 + 1) << 9) + l * 8];
                qk[kt] = __builtin_amdgcn_mfma_f32_16x16x32_bf16(k0v, qf0, qk[kt], 0, 0, 0);
                qk[kt] = __builtin_amdgcn_mfma_f32_16x16x32_bf16(k1v, qf1, qk[kt], 0, 0, 0);
            }
            __builtin_amdgcn_s_setprio(0);

            unsigned short* P = &Pb2[cur][0];
            #pragma unroll
            for (int kt = 0; kt < 4; ++kt) {
                float e0, e1, e2, e3;
                asm("v_exp_f32 %0, %1" : "=v"(e0) : "v"(qk[kt][0]));
                asm("v_exp_f32 %0, %1" : "=v"(e1) : "v"(qk[kt][1]));
                asm("v_exp_f32 %0, %1" : "=v"(e2) : "v"(qk[kt][2]));
                asm("v_exp_f32 %0, %1" : "=v"(e3) : "v"(qk[kt][3]));
                unsigned d0, d1;
                asm("v_cvt_pk_bf16_f32 %0, %1, %2" : "=v"(d0) : "v"(e0), "v"(e1));
                asm("v_cvt_pk_bf16_f32 %0, %1, %2" : "=v"(d1) : "v"(e2), "v"(e3));
                const int chunk = kt * 2 + (grp >> 1);
                *(uint2*)&P[lq * 64 + ((chunk ^ (lq & 7)) * 8) + (grp & 1) * 4] =
                    make_uint2(d0, d1);
            }
        }
        __syncthreads();      // expose P(NKT-1)
        __syncthreads();      // align with Ssum publication
    } else if (w <= 4) {
        // ========== d-consumer: d-tile dt, ALL 5 variants ==========
        const int dt = w - 1;
        const unsigned short* mball = Mmb + (size_t)(b * NV5) * KPAD + grp * 8;
        const unsigned short* vfb = Vf + (((size_t)(hb * NKT)) << 12) + (l << 3);

        f32x4 acc[NV5] = {};          // one d-tile, 5 variants
        s16x8 vfp0, vfp1;

        #pragma unroll 1
        for (int it = 0; it < NKT; ++it) {
            const int cur = it & 1;
            __syncthreads();
            if (it + 1 < NKT) stage(cur ^ 1, it + 1);

            s16x8 pr0, pr1;
            if (it > 0) {
                const unsigned short* Pr = &Pb2[cur ^ 1][0];
                pr0 = *(const s16x8*)&Pr[lq * 64 + ((grp ^ (lq & 7)) * 8)];
                pr1 = *(const s16x8*)&Pr[lq * 64 + (((4 + grp) ^ (lq & 7)) * 8)];
            }
            // prefetch V(it) for this wave's dt (consumed next phase)
            s16x8 nv0 = *(const s16x8*)&vfb[((size_t)(it * 8 + dt * 2 + 0)) << 9];
            s16x8 nv1 = *(const s16x8*)&vfb[((size_t)(it * 8 + dt * 2 + 1)) << 9];

            if (it > 0) {
                const int mi = it - 1;
                __builtin_amdgcn_s_setprio(1);
                #pragma unroll
                for (int v = 0; v < NV5; ++v) {
                    s16x8 mm0 = *(const s16x8*)(mball + (size_t)v * KPAD + mi * 64);
                    s16x8 mm1 = *(const s16x8*)(mball + (size_t)v * KPAD + mi * 64 + 32);
                    acc[v] = __builtin_amdgcn_mfma_f32_16x16x32_bf16(vfp0, pr0 & mm0, acc[v], 0, 0, 0);
                    acc[v] = __builtin_amdgcn_mfma_f32_16x16x32_bf16(vfp1, pr1 & mm1, acc[v], 0, 0, 0);
                }
                __builtin_amdgcn_s_setprio(0);
            }
            vfp0 = nv0; vfp1 = nv1;
        }
        __syncthreads();      // P(NKT-1) visible
        {
            const int mi = NKT - 1;
            const unsigned short* Pr = &Pb2[mi & 1][0];
            s16x8 pr0 = *(const s16x8*)&Pr[lq * 64 + ((grp ^ (lq & 7)) * 8)];
            s16x8 pr1 = *(const s16x8*)&Pr[lq * 64 + (((4 + grp) ^ (lq & 7)) * 8)];
            #pragma unroll
            for (int v = 0; v < NV5; ++v) {
                s16x8 mm0 = *(const s16x8*)(mball + (size_t)v * KPAD + mi * 64);
                s16x8 mm1 = *(const s16x8*)(mball + (size_t)v * KPAD + mi * 64 + 32);
                acc[v] = __builtin_amdgcn_mfma_f32_16x16x32_bf16(vfp0, pr0 & mm0, acc[v], 0, 0, 0);
                acc[v] = __builtin_amdgcn_mfma_f32_16x16x32_bf16(vfp1, pr1 & mm1, acc[v], 0, 0, 0);
            }
        }
        __syncthreads();      // Ssum published

        const int q = q0 + lq;
        if (q < S) {
            #pragma unroll
            for (int v = 0; v < NV5; ++v) {
                const float inv = 1.0f / Ssum[v][lq];
                float* bp = ((v == 0)
                    ? out_h    + (size_t)(b * S + q) * D
                    : out_newh + (size_t)((b * NM + v - 1) * S + q) * D)
                    + hh * 64 + dt * 16 + grp * 4;
                float4 s4;
                s4.x = acc[v][0] * inv; s4.y = acc[v][1] * inv;
                s4.z = acc[v][2] * inv; s4.w = acc[v][3] * inv;
                *(float4*)bp = s4;
            }
        }
    } else {
        // ================= sum wave: 5 variants' denominators =============
        const unsigned short* mball = Mmb + (size_t)(b * NV5) * KPAD + grp * 8;
        s16x8 onesf;
        #pragma unroll
        for (int i = 0; i < 8; ++i) onesf[i] = (short)0x3F80;   // bf16 1.0

        f32x4 accs[NV5] = {};

        #pragma unroll 1
        for (int it = 0; it < NKT; ++it) {
            const int cur = it & 1;
            __syncthreads();
            if (it + 1 < NKT) stage(cur ^ 1, it + 1);

            if (it > 0) {
                const unsigned short* Pr = &Pb2[cur ^ 1][0];
                s16x8 pr0 = *(const s16x8*)&Pr[lq * 64 + ((grp ^ (lq & 7)) * 8)];
                s16x8 pr1 = *(const s16x8*)&Pr[lq * 64 + (((4 + grp) ^ (lq & 7)) * 8)];
                const int mi = it - 1;
                #pragma unroll
                for (int v = 0; v < NV5; ++v) {
                    s16x8 mm0 = *(const s16x8*)(mball + (size_t)v * KPAD + mi * 64);
                    s16x8 mm1 = *(const s16x8*)(mball + (size_t)v * KPAD + mi * 64 + 32);
                    accs[v] = __builtin_amdgcn_mfma_f32_16x16x32_bf16(onesf, pr0 & mm0, accs[v], 0, 0, 0);
                    accs[v] = __builtin_amdgcn_mfma_f32_16x16x32_bf16(onesf, pr1 & mm1, accs[v], 0, 0, 0);
                }
            }
        }
        __syncthreads();      // P(NKT-1) visible
        {
            const int mi = NKT - 1;
            const unsigned short* Pr = &Pb2[mi & 1][0];
            s16x8 pr0 = *(const s16x8*)&Pr[lq * 64 + ((grp ^ (lq & 7)) * 8)];
            s16x8 pr1 = *(const s16x8*)&Pr[lq * 64 + (((4 + grp) ^ (lq & 7)) * 8)];
            #pragma unroll
            for (int v = 0; v < NV5; ++v) {
                s16x8 mm0 = *(const s16x8*)(mball + (size_t)v * KPAD + mi * 64);
                s16x8 mm1 = *(const s16x8*)(mball + (size_t)v * KPAD + mi * 64 + 32);
                accs[v] = __builtin_amdgcn_mfma_f32_16x16x32_bf16(onesf, pr0 & mm0, accs[v], 0, 0, 0);
                accs[v] = __builtin_amdgcn_mfma_f32_16x16x32_bf16(onesf, pr1 & mm1, accs[v], 0, 0, 0);
            }
        }
        if (grp == 0) {
            #pragma unroll
            for (int v = 0; v < NV5; ++v) Ssum[v][lq] = accs[v][0];
        }
        __syncthreads();      // publish Ssum
    }
}

// ---------------------------------------------------------------------------
extern "C" void kernel_launch(void* const* d_in, const int* in_sizes, int n_in,
                              void* d_out, int out_size, void* d_ws, size_t ws_size,
                              hipStream_t stream)
{
    const float* x     = (const float*)d_in[0];
    const int*   masks = (const int*)  d_in[1];
    const float* Wq    = (const float*)d_in[2];
    const float* bq    = (const float*)d_in[3];
    const float* Wk    = (const float*)d_in[4];
    const float* bk    = (const float*)d_in[5];
    const float* Wv    = (const float*)d_in[6];
    const float* bv    = (const float*)d_in[7];

    float* out = (float*)d_out;
    float* out_h    = out;
    float* out_newh = out + OUT_NEWH_OFF;
    float* out_idx  = out + OUT_IDX_OFF;
    float* out_newx = out + OUT_NEWX_OFF;

    unsigned short* Qf  = (unsigned short*)d_ws;
    unsigned short* Kf  = Qf + QF_SZ;
    unsigned short* Vf  = Kf + KF_SZ;
    unsigned short* Mmb = Vf + VF_SZ;      // B*5*KPAD

    // bf16 scratch aliased into the out_newx region (rewritten by the copy
    // blocks of the attention launch, after qkv has consumed it)
    unsigned short* xb = (unsigned short*)out_newx;
    unsigned short* Wb = xb + BSD;

    conv_kernel<<<1634, 256, 0, stream>>>(x, Wq, Wk, Wv, masks, xb, Wb, Mmb,
                                          Qf, Kf, Vf);
    {
        dim3 grid(17, 18);
        qkv_mfma_kernel<<<grid, 256, 0, stream>>>(xb, Wb, bq, bk, bv, Qf, Kf, Vf);
    }
    attn_mfma_kernel<<<NATT + NCPY, 384, 0, stream>>>(Qf, Kf, Vf, Mmb, x,
                                                      out_h, out_newh,
                                                      out_newx, out_idx);
}

// Round 17
// 93.609 us; speedup vs baseline: 1.4428x; 1.4428x over previous
//
#include <hip/hip_runtime.h>

typedef float f32x4 __attribute__((ext_vector_type(4)));
typedef short s16x8 __attribute__((ext_vector_type(8)));

constexpr int B  = 2;
constexpr int S  = 1025;
constexpr int D  = 768;
constexpr int DD = D * D;
constexpr int H  = 12;
constexpr int NM = 4;
constexpr int ROWS = B * S;              // 2050
constexpr int BSD  = B * S * D;          // 1,574,400
constexpr int KPAD = 1088;               // padded key dim for mask table
constexpr int NHB  = B * H;              // 24
constexpr int NQT  = 65;                 // q-tiles of 16
constexpr int NKT  = 17;                 // key-tiles of 64
constexpr int NV5  = 5;                  // softmax variants (base + 4 masks)
constexpr int NATT = NHB * NQT;          // 1560 attention blocks (= 8 x 195)
constexpr int NCPY = 512;                // copy blocks appended to attn grid
constexpr int OUT_NEWH_OFF = BSD;
constexpr int OUT_IDX_OFF  = BSD + NM * BSD;
constexpr int OUT_NEWX_OFF = OUT_IDX_OFF + B * NM;

// fold 1/sqrt(64) * log2(e) into Q so attention uses raw v_exp_f32 (2^x)
#define QSCALE 0.18033688011112042f

// fragment array sizes (u16 elements)
constexpr size_t QF_SZ = (size_t)NHB * NQT * 2 * 512;        // 1,597,440
constexpr size_t KF_SZ = (size_t)NHB * NKT * 4 * 2 * 512;    // 1,671,168
constexpr size_t VF_SZ = KF_SZ;

__device__ __forceinline__ unsigned short f2bf(float f) {
    unsigned u = __builtin_bit_cast(unsigned, f);
    u += 0x7FFF + ((u >> 16) & 1);          // RTNE
    return (unsigned short)(u >> 16);
}

__device__ __forceinline__ void gll16(const void* g, void* l) {
    __builtin_amdgcn_global_load_lds(
        (const __attribute__((address_space(1))) void*)g,
        (__attribute__((address_space(3))) void*)l, 16, 0, 0);
}

// ---------------------------------------------------------------------------
// Kernel 0: convert x, Wq/Wk/Wv to bf16; build 5-variant bf16 mask bitmask
// table; zero the PAD fragment tiles of Qf/Kf/Vf.
// xb/Wb live in the out_newx region of d_out (overwritten by the copy blocks
// of the attention launch, which runs after qkv consumed xb/Wb).
// ---------------------------------------------------------------------------
__global__ __launch_bounds__(256) void conv_kernel(
    const float* __restrict__ x, const float* __restrict__ Wq,
    const float* __restrict__ Wk, const float* __restrict__ Wv,
    const int* __restrict__ masks,
    unsigned short* __restrict__ xb, unsigned short* __restrict__ Wb,
    unsigned short* __restrict__ Mmb,
    unsigned short* __restrict__ Qf, unsigned short* __restrict__ Kf,
    unsigned short* __restrict__ Vf)
{
    constexpr int NX8 = BSD / 8;        // 196800
    constexpr int NW8 = DD / 8;         // 73728
    constexpr int TOT = NX8 + 3 * NW8;  // 417984
    const int stride = gridDim.x * 256;
    const int tid = blockIdx.x * 256 + threadIdx.x;
    for (int c = tid; c < TOT; c += stride) {
        const float* src;
        unsigned short* dst;
        if (c < NX8) { src = x + (size_t)c * 8; dst = xb + (size_t)c * 8; }
        else {
            const int cc = c - NX8;
            const int mt = cc / NW8;
            const int rr = cc - mt * NW8;
            src = ((mt == 0) ? Wq : (mt == 1) ? Wk : Wv) + (size_t)rr * 8;
            dst = Wb + (size_t)mt * DD + (size_t)rr * 8;
        }
        const float4 a = *(const float4*)src;
        const float4 b2 = *(const float4*)(src + 4);
        s16x8 v;
        v[0] = (short)f2bf(a.x);  v[1] = (short)f2bf(a.y);
        v[2] = (short)f2bf(a.z);  v[3] = (short)f2bf(a.w);
        v[4] = (short)f2bf(b2.x); v[5] = (short)f2bf(b2.y);
        v[6] = (short)f2bf(b2.z); v[7] = (short)f2bf(b2.w);
        *(s16x8*)dst = v;
    }
    // mask bitmask table: Mmb[b][vv][KPAD]; vv=0 keeps all real keys
    if (tid < B * NV5 * KPAD) {            // 10880
        const int k    = tid % KPAD;
        const int rest = tid / KPAD;
        const int vv   = rest % NV5;
        const int bb   = rest / NV5;
        unsigned short m;
        if (vv == 0) m = (k < S) ? 0xFFFFu : 0u;
        else m = (k >= 1 && k < S &&
                  masks[(size_t)(bb * NM + vv - 1) * (S - 1) + k - 1]) ? 0xFFFFu : 0u;
        Mmb[tid] = m;
    }
    // zero pad fragment tiles (qkv_mfma writes the valid entries afterwards)
    constexpr int KZ = NHB * 8 * 512;      // 98304 (last key tile: rows 1024..1087)
    for (int i = tid; i < KZ; i += stride) {
        const int hb = i >> 12, off = i & 4095;
        Kf[(((size_t)(hb * NKT + NKT - 1)) << 12) + off] = 0;
        Vf[(((size_t)(hb * NKT + NKT - 1)) << 12) + off] = 0;
    }
    constexpr int QZ = NHB * 2 * 512;      // 24576 (last q tile: rows 1024..1039)
    for (int i = tid; i < QZ; i += stride) {
        const int hb = i >> 10, off = i & 1023;
        Qf[(((size_t)(hb * NQT + NQT - 1) * 2) << 9) + off] = 0;
    }
}

// ---------------------------------------------------------------------------
// Kernel 1: QKV projection as ONE 128x128-tile bf16 MFMA GEMM over the
// concatenated weight matrix [2304][768] (tiles 0-5 = Q, 6-11 = K, 12-17 = V).
// 256 thr = 4 waves in 2x2, each wave a 64x64 quadrant, BK=64, double-
// buffered gll staging. Epilogue scatters to MFMA FRAGMENT ORDER:
//   Qf[hb][qt][kh][lane][8]  elem = Q[qt*16+(l&15)][(l>>4)*8+kh*32+e]*QSCALE
//   Kf[hb][tile][kt][kh][lane][8] = K[tile*64+kt*16+(l&15)][(l>>4)*8+kh*32+e]
//   Vf[hb][tile][dt][kh][lane][8] = V[tile*64+(l>>4)*8+kh*32+e][dt*16+(l&15)]
// ---------------------------------------------------------------------------
__global__ __launch_bounds__(256, 2) void qkv_mfma_kernel(
    const unsigned short* __restrict__ xb, const unsigned short* __restrict__ Wb,
    const float* __restrict__ bq, const float* __restrict__ bk,
    const float* __restrict__ bv,
    unsigned short* __restrict__ Qf, unsigned short* __restrict__ Kf,
    unsigned short* __restrict__ Vf)
{
    __shared__ __align__(16) unsigned short Xs[2][128 * 64];
    __shared__ __align__(16) unsigned short Wl[2][128 * 64];

    const int t = threadIdx.x;
    const int row0 = blockIdx.x * 128;
    const int cy = blockIdx.y;           // 0..17
    const int mt = cy / 6;
    const int col0 = (cy % 6) * 128;     // within-matrix column base
    const float* bias = (mt == 0) ? bq : (mt == 1) ? bk : bv;
    const unsigned short* Wsrc = Wb + (size_t)mt * DD;

    const int w = t >> 6, l = t & 63, lq = l & 15, grp = l >> 4;
    const int wr = w >> 1, wc = w & 1;   // wave quadrant (2x2)

    auto stage = [&](int buf, int k0) {
        #pragma unroll
        for (int i = 0; i < 4; ++i) {
            const int slot = i * 256 + t;           // 0..1023 chunks
            const int r = slot >> 3, cl = slot & 7;
            const int cg = cl ^ (r & 7);
            int row = row0 + r; if (row > ROWS - 1) row = ROWS - 1;
            gll16(xb + (size_t)row * D + k0 + cg * 8, &Xs[buf][slot * 8]);
            gll16(Wsrc + (size_t)(col0 + r) * D + k0 + cg * 8, &Wl[buf][slot * 8]);
        }
    };

    f32x4 acc[4][4] = {};
    stage(0, 0);

    for (int ks = 0; ks < 12; ++ks) {
        const int cur = ks & 1;
        __syncthreads();
        if (ks + 1 < 12) stage(cur ^ 1, (ks + 1) * 64);

        s16x8 a[4][2], bf[4][2];
        #pragma unroll
        for (int i = 0; i < 4; ++i) {
            const int xr = wr * 64 + i * 16 + lq;
            #pragma unroll
            for (int kh = 0; kh < 2; ++kh)
                a[i][kh] = *(const s16x8*)&Xs[cur][xr * 64 + (((kh * 4 + grp) ^ (xr & 7)) * 8)];
        }
        #pragma unroll
        for (int j = 0; j < 4; ++j) {
            const int wrow = wc * 64 + j * 16 + lq;
            #pragma unroll
            for (int kh = 0; kh < 2; ++kh)
                bf[j][kh] = *(const s16x8*)&Wl[cur][wrow * 64 + (((kh * 4 + grp) ^ (wrow & 7)) * 8)];
        }
        #pragma unroll
        for (int i = 0; i < 4; ++i)
            #pragma unroll
            for (int j = 0; j < 4; ++j) {
                acc[i][j] = __builtin_amdgcn_mfma_f32_16x16x32_bf16(a[i][0], bf[j][0], acc[i][j], 0, 0, 0);
                acc[i][j] = __builtin_amdgcn_mfma_f32_16x16x32_bf16(a[i][1], bf[j][1], acc[i][j], 0, 0, 0);
            }
    }

    // epilogue: bias add + fragment-order scatter (bf16)
    #pragma unroll
    for (int j = 0; j < 4; ++j) {
        const int col = col0 + wc * 64 + j * 16 + lq;   // 0..767 within matrix
        const float bv_ = bias[col];
        #pragma unroll
        for (int i = 0; i < 4; ++i) {
            #pragma unroll
            for (int r = 0; r < 4; ++r) {
                const int row = row0 + wr * 64 + i * 16 + grp * 4 + r;
                if (row >= ROWS) continue;
                const float raw = acc[i][j][r] + bv_;
                const int bb = (row >= S) ? 1 : 0;
                const int s  = row - bb * S;
                const int hb2 = bb * H + (col >> 6);
                const int d   = col & 63;
                if (mt == 0) {
                    const size_t idx = (((size_t)(hb2 * NQT + (s >> 4)) * 2 + (d >> 5)) << 9)
                                     + (((((d >> 3) & 3) << 4) + (s & 15)) << 3) + (d & 7);
                    Qf[idx] = f2bf(raw * QSCALE);
                } else if (mt == 1) {
                    const size_t idx = ((((size_t)(hb2 * NKT + (s >> 6)) * 4 + ((s >> 4) & 3)) * 2 + (d >> 5)) << 9)
                                     + (((((d >> 3) & 3) << 4) + (s & 15)) << 3) + (d & 7);
                    Kf[idx] = f2bf(raw);
                } else {
                    const int kk = s & 63;
                    const size_t idx = ((((size_t)(hb2 * NKT + (s >> 6)) * 4 + (d >> 4)) * 2 + (kk >> 5)) << 9)
                                     + (((((kk >> 3) & 3) << 4) + (d & 15)) << 3) + (kk & 7);
                    Vf[idx] = f2bf(raw);
                }
            }
        }
    }
}

// ---------------------------------------------------------------------------
// Kernel 2: producer/consumer MFMA attention + fused new_x copy (round-10
// structure, measured best; + mask bitmask PREFETCH one phase ahead so the
// consumer's mm loads have a full phase to land instead of being issued at
// use). Blocks < NATT: 384 thr = 6 waves over ONE 16-q tile of one (b,h).
// Blocks >= NATT: new_x broadcast copy + img_idx.
// ---------------------------------------------------------------------------
__global__ __launch_bounds__(384) void attn_mfma_kernel(
    const unsigned short* __restrict__ Qf, const unsigned short* __restrict__ Kf,
    const unsigned short* __restrict__ Vf, const unsigned short* __restrict__ Mmb,
    const float* __restrict__ x,
    float* __restrict__ out_h, float* __restrict__ out_newh,
    float* __restrict__ out_newx, float* __restrict__ out_idx)
{
    if (blockIdx.x >= NATT) {
        // ---- fused tail: new_x broadcast copy + img_idx ----
        const int cb = blockIdx.x - NATT;
        const int SLAB4  = S * D / 4;
        const int TOTAL4 = B * NM * SLAB4;
        const float4* x4 = (const float4*)x;
        float4* o4 = (float4*)out_newx;
        for (int f = cb * 384 + threadIdx.x; f < TOTAL4; f += NCPY * 384) {
            const int bm  = f / SLAB4;
            const int rem = f - bm * SLAB4;
            o4[f] = x4[(bm >> 2) * SLAB4 + rem];
        }
        if (cb == 0 && threadIdx.x < B * NM)
            out_idx[threadIdx.x] = (float)(threadIdx.x >> 2);
        return;
    }

    __shared__ __align__(16) unsigned short KVl[2][2][4096];  // [buf][K/V] 32KB
    __shared__ __align__(16) unsigned short Pb2[2][1024];     // shared P, 4KB

    const int orig = blockIdx.x;
    const int wgid = (orig & 7) * 195 + (orig >> 3);   // 1560 = 8 x 195
    const int hb = wgid / NQT;           // 0..23
    const int qt = wgid - hb * NQT;      // 0..64
    const int b  = hb / H, hh = hb - b * H;
    const int q0 = qt * 16;

    const int t = threadIdx.x;
    const int w = t >> 6, l = t & 63;
    const int lq = l & 15, grp = l >> 4;

    const unsigned short* kfT = Kf + (((size_t)(hb * NKT)) << 12);
    const unsigned short* vfT = Vf + (((size_t)(hb * NKT)) << 12);

    // all threads cooperatively stage tile -> LDS buf (flat, lane-linear)
    auto stage = [&](int buf, int tile) {
        const unsigned short* ks = kfT + ((size_t)tile << 12);
        const unsigned short* vs = vfT + ((size_t)tile << 12);
        #pragma unroll
        for (int i = 0; i < 3; ++i) {
            const int s = t + i * 384;
            if (s < 512)       gll16(ks + s * 8, &KVl[buf][0][s * 8]);
            else if (s < 1024) gll16(vs + (s - 512) * 8, &KVl[buf][1][(s - 512) * 8]);
        }
    };

    stage(0, 0);

    if (w == 0) {
        // ================= producer: QK + exp + P =================
        s16x8 qf0, qf1;
        {
            const unsigned short* p = Qf + (((size_t)(hb * NQT + qt) * 2) << 9) + (l << 3);
            qf0 = *(const s16x8*)p;
            qf1 = *(const s16x8*)(p + 512);
        }
        #pragma unroll
        for (int it = 0; it < NKT; ++it) {
            const int cur = it & 1;
            __syncthreads();
            if (it + 1 < NKT) stage(cur ^ 1, it + 1);

            s16x8 kf[4][2];
            #pragma unroll
            for (int kt = 0; kt < 4; ++kt)
                #pragma unroll
                for (int kh = 0; kh < 2; ++kh)
                    kf[kt][kh] = *(const s16x8*)&KVl[cur][0][((kt * 2 + kh) << 9) + l * 8];

            f32x4 qk[4] = {};
            __builtin_amdgcn_s_setprio(1);
            #pragma unroll
            for (int kt = 0; kt < 4; ++kt) {
                qk[kt] = __builtin_amdgcn_mfma_f32_16x16x32_bf16(kf[kt][0], qf0, qk[kt], 0, 0, 0);
                qk[kt] = __builtin_amdgcn_mfma_f32_16x16x32_bf16(kf[kt][1], qf1, qk[kt], 0, 0, 0);
            }
            __builtin_amdgcn_s_setprio(0);

            unsigned short* P = &Pb2[cur][0];
            #pragma unroll
            for (int kt = 0; kt < 4; ++kt) {
                float e0, e1, e2, e3;
                asm("v_exp_f32 %0, %1" : "=v"(e0) : "v"(qk[kt][0]));
                asm("v_exp_f32 %0, %1" : "=v"(e1) : "v"(qk[kt][1]));
                asm("v_exp_f32 %0, %1" : "=v"(e2) : "v"(qk[kt][2]));
                asm("v_exp_f32 %0, %1" : "=v"(e3) : "v"(qk[kt][3]));
                unsigned d0, d1;
                asm("v_cvt_pk_bf16_f32 %0, %1, %2" : "=v"(d0) : "v"(e0), "v"(e1));
                asm("v_cvt_pk_bf16_f32 %0, %1, %2" : "=v"(d1) : "v"(e2), "v"(e3));
                const int chunk = kt * 2 + (grp >> 1);
                *(uint2*)&P[lq * 64 + ((chunk ^ (lq & 7)) * 8) + (grp & 1) * 4] =
                    make_uint2(d0, d1);
            }
        }
        __syncthreads();      // expose P(NKT-1) to consumers
    } else {
        // ================= consumer: one variant's PV =================
        const int vv = w - 1;                               // 0..4
        const unsigned short* mbase = Mmb + (size_t)(b * NV5 + vv) * KPAD + grp * 8;

        s16x8 onesf;
        #pragma unroll
        for (int i = 0; i < 8; ++i) onesf[i] = (short)0x3F80;   // bf16 1.0

        f32x4 acc[5] = {};    // dt 0..3 = O^T tiles, 4 = sums
        s16x8 vfp[4][2];
        s16x8 mmA0, mmA1;     // masks for tile it-1 (prefetched last phase)

        auto pv = [&](s16x8 ea0, s16x8 ea1, s16x8 mm0, s16x8 mm1) {
            s16x8 pa0 = ea0 & mm0;
            s16x8 pa1 = ea1 & mm1;
            __builtin_amdgcn_s_setprio(1);
            #pragma unroll
            for (int dt = 0; dt < 4; ++dt)
                acc[dt] = __builtin_amdgcn_mfma_f32_16x16x32_bf16(vfp[dt][0], pa0, acc[dt], 0, 0, 0);
            acc[4] = __builtin_amdgcn_mfma_f32_16x16x32_bf16(onesf, pa0, acc[4], 0, 0, 0);
            #pragma unroll
            for (int dt = 0; dt < 4; ++dt)
                acc[dt] = __builtin_amdgcn_mfma_f32_16x16x32_bf16(vfp[dt][1], pa1, acc[dt], 0, 0, 0);
            acc[4] = __builtin_amdgcn_mfma_f32_16x16x32_bf16(onesf, pa1, acc[4], 0, 0, 0);
            __builtin_amdgcn_s_setprio(0);
        };

        // prefetch masks for tile 0 (consumed when it=1 processes mi=0)
        mmA0 = *(const s16x8*)(mbase + 0);
        mmA1 = *(const s16x8*)(mbase + 32);

        #pragma unroll
        for (int it = 0; it < NKT; ++it) {
            const int cur = it & 1;
            __syncthreads();
            if (it + 1 < NKT) stage(cur ^ 1, it + 1);

            // P(it-1) reads first (shortest lgkm wait for PV below)
            s16x8 pr0, pr1;
            if (it > 0) {
                const unsigned short* Pr = &Pb2[cur ^ 1][0];
                pr0 = *(const s16x8*)&Pr[lq * 64 + ((grp ^ (lq & 7)) * 8)];
                pr1 = *(const s16x8*)&Pr[lq * 64 + (((4 + grp) ^ (lq & 7)) * 8)];
            }
            // V(it) fragment reads (consumed next iteration)
            s16x8 vfc[4][2];
            #pragma unroll
            for (int dt = 0; dt < 4; ++dt)
                #pragma unroll
                for (int kh = 0; kh < 2; ++kh)
                    vfc[dt][kh] = *(const s16x8*)&KVl[cur][1][((dt * 2 + kh) << 9) + l * 8];
            // mask prefetch for tile it (consumed next iteration as mi=it)
            s16x8 mmB0 = *(const s16x8*)(mbase + it * 64);
            s16x8 mmB1 = *(const s16x8*)(mbase + it * 64 + 32);

            if (it > 0) pv(pr0, pr1, mmA0, mmA1);

            #pragma unroll
            for (int dt = 0; dt < 4; ++dt) {
                vfp[dt][0] = vfc[dt][0];
                vfp[dt][1] = vfc[dt][1];
            }
            mmA0 = mmB0; mmA1 = mmB1;
        }
        __syncthreads();      // P(NKT-1) visible
        {
            const unsigned short* Pr = &Pb2[(NKT - 1) & 1][0];
            s16x8 pr0 = *(const s16x8*)&Pr[lq * 64 + ((grp ^ (lq & 7)) * 8)];
            s16x8 pr1 = *(const s16x8*)&Pr[lq * 64 + (((4 + grp) ^ (lq & 7)) * 8)];
            pv(pr0, pr1, mmA0, mmA1);
        }

        const int q = q0 + lq;
        if (q < S) {
            const float inv = 1.0f / acc[4][0];
            float* bp = ((vv == 0)
                ? out_h    + (size_t)(b * S + q) * D
                : out_newh + (size_t)((b * NM + vv - 1) * S + q) * D) + hh * 64 + grp * 4;
            #pragma unroll
            for (int dt = 0; dt < 4; ++dt) {
                float4 s4;
                s4.x = acc[dt][0] * inv; s4.y = acc[dt][1] * inv;
                s4.z = acc[dt][2] * inv; s4.w = acc[dt][3] * inv;
                *(float4*)(bp + dt * 16) = s4;
            }
        }
    }
}

// ---------------------------------------------------------------------------
extern "C" void kernel_launch(void* const* d_in, const int* in_sizes, int n_in,
                              void* d_out, int out_size, void* d_ws, size_t ws_size,
                              hipStream_t stream)
{
    const float* x     = (const float*)d_in[0];
    const int*   masks = (const int*)  d_in[1];
    const float* Wq    = (const float*)d_in[2];
    const float* bq    = (const float*)d_in[3];
    const float* Wk    = (const float*)d_in[4];
    const float* bk    = (const float*)d_in[5];
    const float* Wv    = (const float*)d_in[6];
    const float* bv    = (const float*)d_in[7];

    float* out = (float*)d_out;
    float* out_h    = out;
    float* out_newh = out + OUT_NEWH_OFF;
    float* out_idx  = out + OUT_IDX_OFF;
    float* out_newx = out + OUT_NEWX_OFF;

    unsigned short* Qf  = (unsigned short*)d_ws;
    unsigned short* Kf  = Qf + QF_SZ;
    unsigned short* Vf  = Kf + KF_SZ;
    unsigned short* Mmb = Vf + VF_SZ;      // B*5*KPAD

    // bf16 scratch aliased into the out_newx region (rewritten by the copy
    // blocks of the attention launch, after qkv has consumed it)
    unsigned short* xb = (unsigned short*)out_newx;
    unsigned short* Wb = xb + BSD;

    conv_kernel<<<1634, 256, 0, stream>>>(x, Wq, Wk, Wv, masks, xb, Wb, Mmb,
                                          Qf, Kf, Vf);
    {
        dim3 grid(17, 18);
        qkv_mfma_kernel<<<grid, 256, 0, stream>>>(xb, Wb, bq, bk, bv, Qf, Kf, Vf);
    }
    attn_mfma_kernel<<<NATT + NCPY, 384, 0, stream>>>(Qf, Kf, Vf, Mmb, x,
                                                      out_h, out_newh,
                                                      out_newx, out_idx);
}

// Round 18
// 83.283 us; speedup vs baseline: 1.6217x; 1.1240x over previous
//
#include <hip/hip_runtime.h>

typedef float f32x4 __attribute__((ext_vector_type(4)));
typedef short s16x8 __attribute__((ext_vector_type(8)));

constexpr int B  = 2;
constexpr int S  = 1025;
constexpr int D  = 768;
constexpr int DD = D * D;
constexpr int H  = 12;
constexpr int NM = 4;
constexpr int ROWS = B * S;              // 2050
constexpr int BSD  = B * S * D;          // 1,574,400
constexpr int KPAD = 1088;               // padded key dim for mask table
constexpr int NHB  = B * H;              // 24
constexpr int NQT  = 65;                 // q-tiles of 16
constexpr int NKT  = 17;                 // key-tiles of 64
constexpr int NV5  = 5;                  // softmax variants (base + 4 masks)
constexpr int NATT = NHB * NQT;          // 1560 attention blocks (= 8 x 195)
constexpr int NQKV = 33 * 18;            // 594 qkv blocks (64x128 tiles)
constexpr int NCPY = 512;                // copy blocks appended to qkv grid
constexpr int OUT_NEWH_OFF = BSD;
constexpr int OUT_IDX_OFF  = BSD + NM * BSD;
constexpr int OUT_NEWX_OFF = OUT_IDX_OFF + B * NM;

// fold 1/sqrt(64) * log2(e) into Q so attention uses raw v_exp_f32 (2^x)
#define QSCALE 0.18033688011112042f

// fragment array sizes (u16 elements)
constexpr size_t QF_SZ = (size_t)NHB * NQT * 2 * 512;        // 1,597,440
constexpr size_t KF_SZ = (size_t)NHB * NKT * 4 * 2 * 512;    // 1,671,168
constexpr size_t VF_SZ = KF_SZ;

__device__ __forceinline__ unsigned short f2bf(float f) {
    unsigned u = __builtin_bit_cast(unsigned, f);
    u += 0x7FFF + ((u >> 16) & 1);          // RTNE
    return (unsigned short)(u >> 16);
}

__device__ __forceinline__ void gll16(const void* g, void* l) {
    __builtin_amdgcn_global_load_lds(
        (const __attribute__((address_space(1))) void*)g,
        (__attribute__((address_space(3))) void*)l, 16, 0, 0);
}

// ---------------------------------------------------------------------------
// Kernel 0: convert x, Wq/Wk/Wv to bf16; build 5-variant bf16 mask bitmask
// table; zero the PAD fragment tiles of Qf/Kf/Vf.
// xb/Wb live at the START of the out_newh region of d_out (6.7MB of 25MB) —
// consumed by qkv, then fully overwritten by the attention launch.
// ---------------------------------------------------------------------------
__global__ __launch_bounds__(256) void conv_kernel(
    const float* __restrict__ x, const float* __restrict__ Wq,
    const float* __restrict__ Wk, const float* __restrict__ Wv,
    const int* __restrict__ masks,
    unsigned short* __restrict__ xb, unsigned short* __restrict__ Wb,
    unsigned short* __restrict__ Mmb,
    unsigned short* __restrict__ Qf, unsigned short* __restrict__ Kf,
    unsigned short* __restrict__ Vf)
{
    constexpr int NX8 = BSD / 8;        // 196800
    constexpr int NW8 = DD / 8;         // 73728
    constexpr int TOT = NX8 + 3 * NW8;  // 417984
    const int stride = gridDim.x * 256;
    const int tid = blockIdx.x * 256 + threadIdx.x;
    for (int c = tid; c < TOT; c += stride) {
        const float* src;
        unsigned short* dst;
        if (c < NX8) { src = x + (size_t)c * 8; dst = xb + (size_t)c * 8; }
        else {
            const int cc = c - NX8;
            const int mt = cc / NW8;
            const int rr = cc - mt * NW8;
            src = ((mt == 0) ? Wq : (mt == 1) ? Wk : Wv) + (size_t)rr * 8;
            dst = Wb + (size_t)mt * DD + (size_t)rr * 8;
        }
        const float4 a = *(const float4*)src;
        const float4 b2 = *(const float4*)(src + 4);
        s16x8 v;
        v[0] = (short)f2bf(a.x);  v[1] = (short)f2bf(a.y);
        v[2] = (short)f2bf(a.z);  v[3] = (short)f2bf(a.w);
        v[4] = (short)f2bf(b2.x); v[5] = (short)f2bf(b2.y);
        v[6] = (short)f2bf(b2.z); v[7] = (short)f2bf(b2.w);
        *(s16x8*)dst = v;
    }
    // mask bitmask table: Mmb[b][vv][KPAD]; vv=0 keeps all real keys
    if (tid < B * NV5 * KPAD) {            // 10880
        const int k    = tid % KPAD;
        const int rest = tid / KPAD;
        const int vv   = rest % NV5;
        const int bb   = rest / NV5;
        unsigned short m;
        if (vv == 0) m = (k < S) ? 0xFFFFu : 0u;
        else m = (k >= 1 && k < S &&
                  masks[(size_t)(bb * NM + vv - 1) * (S - 1) + k - 1]) ? 0xFFFFu : 0u;
        Mmb[tid] = m;
    }
    // zero pad fragment tiles (qkv_mfma writes the valid entries afterwards)
    constexpr int KZ = NHB * 8 * 512;      // 98304 (last key tile: rows 1024..1087)
    for (int i = tid; i < KZ; i += stride) {
        const int hb = i >> 12, off = i & 4095;
        Kf[(((size_t)(hb * NKT + NKT - 1)) << 12) + off] = 0;
        Vf[(((size_t)(hb * NKT + NKT - 1)) << 12) + off] = 0;
    }
    constexpr int QZ = NHB * 2 * 512;      // 24576 (last q tile: rows 1024..1039)
    for (int i = tid; i < QZ; i += stride) {
        const int hb = i >> 10, off = i & 1023;
        Qf[(((size_t)(hb * NQT + NQT - 1) * 2) << 9) + off] = 0;
    }
}

// ---------------------------------------------------------------------------
// Kernel 1: QKV projection, 64x128-tile bf16 MFMA GEMM over the concatenated
// weight matrix [2304][768] (cy 0-5 = Q, 6-11 = K, 12-17 = V cols), grid
// flattened 1D: blocks < NQKV do GEMM (bx = id%33 row-tile, cy = id/33);
// blocks >= NQKV do the new_x broadcast copy + img_idx (independent of qkv,
// fills the CUs idle during qkv's 2.3-blocks/CU imbalance).
// 4 waves side-by-side: wave w covers cols [w*32, w*32+32) x all 64 rows.
// BK=64, double-buffered gll staging (48KB LDS -> 3 blocks/CU).
// Epilogue scatters to MFMA FRAGMENT ORDER (unchanged):
//   Qf[hb][qt][kh][lane][8]  elem = Q[qt*16+(l&15)][(l>>4)*8+kh*32+e]*QSCALE
//   Kf[hb][tile][kt][kh][lane][8] = K[tile*64+kt*16+(l&15)][(l>>4)*8+kh*32+e]
//   Vf[hb][tile][dt][kh][lane][8] = V[tile*64+(l>>4)*8+kh*32+e][dt*16+(l&15)]
// ---------------------------------------------------------------------------
__global__ __launch_bounds__(256, 2) void qkv_mfma_kernel(
    const unsigned short* __restrict__ xb, const unsigned short* __restrict__ Wb,
    const float* __restrict__ bq, const float* __restrict__ bk,
    const float* __restrict__ bv,
    unsigned short* __restrict__ Qf, unsigned short* __restrict__ Kf,
    unsigned short* __restrict__ Vf,
    const float* __restrict__ x,
    float* __restrict__ out_newx, float* __restrict__ out_idx)
{
    if (blockIdx.x >= NQKV) {
        // ---- fused: new_x broadcast copy + img_idx ----
        const int cb = blockIdx.x - NQKV;
        const int SLAB4  = S * D / 4;
        const int TOTAL4 = B * NM * SLAB4;
        const float4* x4 = (const float4*)x;
        float4* o4 = (float4*)out_newx;
        for (int f = cb * 256 + threadIdx.x; f < TOTAL4; f += NCPY * 256) {
            const int bm  = f / SLAB4;
            const int rem = f - bm * SLAB4;
            o4[f] = x4[(bm >> 2) * SLAB4 + rem];
        }
        if (cb == 0 && threadIdx.x < B * NM)
            out_idx[threadIdx.x] = (float)(threadIdx.x >> 2);
        return;
    }

    __shared__ __align__(16) unsigned short Xs[2][64 * 64];    // 16KB
    __shared__ __align__(16) unsigned short Wl[2][128 * 64];   // 32KB

    const int t = threadIdx.x;
    const int bx = blockIdx.x % 33;
    const int cy = blockIdx.x / 33;      // 0..17
    const int row0 = bx * 64;
    const int mt = cy / 6;
    const int col0 = (cy % 6) * 128;     // within-matrix column base
    const float* bias = (mt == 0) ? bq : (mt == 1) ? bk : bv;
    const unsigned short* Wsrc = Wb + (size_t)mt * DD;

    const int w = t >> 6, l = t & 63, lq = l & 15, grp = l >> 4;

    auto stage = [&](int buf, int k0) {
        #pragma unroll
        for (int i = 0; i < 2; ++i) {               // X: 512 chunks
            const int slot = i * 256 + t;
            const int r = slot >> 3, cl = slot & 7;
            const int cg = cl ^ (r & 7);
            int row = row0 + r; if (row > ROWS - 1) row = ROWS - 1;
            gll16(xb + (size_t)row * D + k0 + cg * 8, &Xs[buf][slot * 8]);
        }
        #pragma unroll
        for (int i = 0; i < 4; ++i) {               // W: 1024 chunks
            const int slot = i * 256 + t;
            const int r = slot >> 3, cl = slot & 7;
            const int cg = cl ^ (r & 7);
            gll16(Wsrc + (size_t)(col0 + r) * D + k0 + cg * 8, &Wl[buf][slot * 8]);
        }
    };

    f32x4 acc[4][2] = {};
    stage(0, 0);

    for (int ks = 0; ks < 12; ++ks) {
        const int cur = ks & 1;
        __syncthreads();
        if (ks + 1 < 12) stage(cur ^ 1, (ks + 1) * 64);

        s16x8 a[4][2], bf[2][2];
        #pragma unroll
        for (int i = 0; i < 4; ++i) {
            const int xr = i * 16 + lq;
            #pragma unroll
            for (int kh = 0; kh < 2; ++kh)
                a[i][kh] = *(const s16x8*)&Xs[cur][xr * 64 + (((kh * 4 + grp) ^ (xr & 7)) * 8)];
        }
        #pragma unroll
        for (int j = 0; j < 2; ++j) {
            const int wrow = w * 32 + j * 16 + lq;
            #pragma unroll
            for (int kh = 0; kh < 2; ++kh)
                bf[j][kh] = *(const s16x8*)&Wl[cur][wrow * 64 + (((kh * 4 + grp) ^ (wrow & 7)) * 8)];
        }
        #pragma unroll
        for (int i = 0; i < 4; ++i)
            #pragma unroll
            for (int j = 0; j < 2; ++j) {
                acc[i][j] = __builtin_amdgcn_mfma_f32_16x16x32_bf16(a[i][0], bf[j][0], acc[i][j], 0, 0, 0);
                acc[i][j] = __builtin_amdgcn_mfma_f32_16x16x32_bf16(a[i][1], bf[j][1], acc[i][j], 0, 0, 0);
            }
    }

    // epilogue: bias add + fragment-order scatter (bf16)
    #pragma unroll
    for (int j = 0; j < 2; ++j) {
        const int col = col0 + w * 32 + j * 16 + lq;    // 0..767 within matrix
        const float bv_ = bias[col];
        #pragma unroll
        for (int i = 0; i < 4; ++i) {
            #pragma unroll
            for (int r = 0; r < 4; ++r) {
                const int row = row0 + i * 16 + grp * 4 + r;
                if (row >= ROWS) continue;
                const float raw = acc[i][j][r] + bv_;
                const int bb = (row >= S) ? 1 : 0;
                const int s  = row - bb * S;
                const int hb2 = bb * H + (col >> 6);
                const int d   = col & 63;
                if (mt == 0) {
                    const size_t idx = (((size_t)(hb2 * NQT + (s >> 4)) * 2 + (d >> 5)) << 9)
                                     + (((((d >> 3) & 3) << 4) + (s & 15)) << 3) + (d & 7);
                    Qf[idx] = f2bf(raw * QSCALE);
                } else if (mt == 1) {
                    const size_t idx = ((((size_t)(hb2 * NKT + (s >> 6)) * 4 + ((s >> 4) & 3)) * 2 + (d >> 5)) << 9)
                                     + (((((d >> 3) & 3) << 4) + (s & 15)) << 3) + (d & 7);
                    Kf[idx] = f2bf(raw);
                } else {
                    const int kk = s & 63;
                    const size_t idx = ((((size_t)(hb2 * NKT + (s >> 6)) * 4 + (d >> 4)) * 2 + (kk >> 5)) << 9)
                                     + (((((kk >> 3) & 3) << 4) + (d & 15)) << 3) + (kk & 7);
                    Vf[idx] = f2bf(raw);
                }
            }
        }
    }
}

// ---------------------------------------------------------------------------
// Kernel 2: producer/consumer MFMA attention (round-17 best: r10 structure +
// mask prefetch one phase ahead). Pure attention grid (copy moved to qkv
// launch). 384 thr = 6 waves over ONE 16-q tile of one (b,h).
// ---------------------------------------------------------------------------
__global__ __launch_bounds__(384) void attn_mfma_kernel(
    const unsigned short* __restrict__ Qf, const unsigned short* __restrict__ Kf,
    const unsigned short* __restrict__ Vf, const unsigned short* __restrict__ Mmb,
    float* __restrict__ out_h, float* __restrict__ out_newh)
{
    __shared__ __align__(16) unsigned short KVl[2][2][4096];  // [buf][K/V] 32KB
    __shared__ __align__(16) unsigned short Pb2[2][1024];     // shared P, 4KB

    const int orig = blockIdx.x;
    const int wgid = (orig & 7) * 195 + (orig >> 3);   // 1560 = 8 x 195
    const int hb = wgid / NQT;           // 0..23
    const int qt = wgid - hb * NQT;      // 0..64
    const int b  = hb / H, hh = hb - b * H;
    const int q0 = qt * 16;

    const int t = threadIdx.x;
    const int w = t >> 6, l = t & 63;
    const int lq = l & 15, grp = l >> 4;

    const unsigned short* kfT = Kf + (((size_t)(hb * NKT)) << 12);
    const unsigned short* vfT = Vf + (((size_t)(hb * NKT)) << 12);

    // all threads cooperatively stage tile -> LDS buf (flat, lane-linear)
    auto stage = [&](int buf, int tile) {
        const unsigned short* ks = kfT + ((size_t)tile << 12);
        const unsigned short* vs = vfT + ((size_t)tile << 12);
        #pragma unroll
        for (int i = 0; i < 3; ++i) {
            const int s = t + i * 384;
            if (s < 512)       gll16(ks + s * 8, &KVl[buf][0][s * 8]);
            else if (s < 1024) gll16(vs + (s - 512) * 8, &KVl[buf][1][(s - 512) * 8]);
        }
    };

    stage(0, 0);

    if (w == 0) {
        // ================= producer: QK + exp + P =================
        s16x8 qf0, qf1;
        {
            const unsigned short* p = Qf + (((size_t)(hb * NQT + qt) * 2) << 9) + (l << 3);
            qf0 = *(const s16x8*)p;
            qf1 = *(const s16x8*)(p + 512);
        }
        #pragma unroll
        for (int it = 0; it < NKT; ++it) {
            const int cur = it & 1;
            __syncthreads();
            if (it + 1 < NKT) stage(cur ^ 1, it + 1);

            s16x8 kf[4][2];
            #pragma unroll
            for (int kt = 0; kt < 4; ++kt)
                #pragma unroll
                for (int kh = 0; kh < 2; ++kh)
                    kf[kt][kh] = *(const s16x8*)&KVl[cur][0][((kt * 2 + kh) << 9) + l * 8];

            f32x4 qk[4] = {};
            __builtin_amdgcn_s_setprio(1);
            #pragma unroll
            for (int kt = 0; kt < 4; ++kt) {
                qk[kt] = __builtin_amdgcn_mfma_f32_16x16x32_bf16(kf[kt][0], qf0, qk[kt], 0, 0, 0);
                qk[kt] = __builtin_amdgcn_mfma_f32_16x16x32_bf16(kf[kt][1], qf1, qk[kt], 0, 0, 0);
            }
            __builtin_amdgcn_s_setprio(0);

            unsigned short* P = &Pb2[cur][0];
            #pragma unroll
            for (int kt = 0; kt < 4; ++kt) {
                float e0, e1, e2, e3;
                asm("v_exp_f32 %0, %1" : "=v"(e0) : "v"(qk[kt][0]));
                asm("v_exp_f32 %0, %1" : "=v"(e1) : "v"(qk[kt][1]));
                asm("v_exp_f32 %0, %1" : "=v"(e2) : "v"(qk[kt][2]));
                asm("v_exp_f32 %0, %1" : "=v"(e3) : "v"(qk[kt][3]));
                unsigned d0, d1;
                asm("v_cvt_pk_bf16_f32 %0, %1, %2" : "=v"(d0) : "v"(e0), "v"(e1));
                asm("v_cvt_pk_bf16_f32 %0, %1, %2" : "=v"(d1) : "v"(e2), "v"(e3));
                const int chunk = kt * 2 + (grp >> 1);
                *(uint2*)&P[lq * 64 + ((chunk ^ (lq & 7)) * 8) + (grp & 1) * 4] =
                    make_uint2(d0, d1);
            }
        }
        __syncthreads();      // expose P(NKT-1) to consumers
    } else {
        // ================= consumer: one variant's PV =================
        const int vv = w - 1;                               // 0..4
        const unsigned short* mbase = Mmb + (size_t)(b * NV5 + vv) * KPAD + grp * 8;

        s16x8 onesf;
        #pragma unroll
        for (int i = 0; i < 8; ++i) onesf[i] = (short)0x3F80;   // bf16 1.0

        f32x4 acc[5] = {};    // dt 0..3 = O^T tiles, 4 = sums
        s16x8 vfp[4][2];
        s16x8 mmA0, mmA1;     // masks for tile it-1 (prefetched last phase)

        auto pv = [&](s16x8 ea0, s16x8 ea1, s16x8 mm0, s16x8 mm1) {
            s16x8 pa0 = ea0 & mm0;
            s16x8 pa1 = ea1 & mm1;
            __builtin_amdgcn_s_setprio(1);
            #pragma unroll
            for (int dt = 0; dt < 4; ++dt)
                acc[dt] = __builtin_amdgcn_mfma_f32_16x16x32_bf16(vfp[dt][0], pa0, acc[dt], 0, 0, 0);
            acc[4] = __builtin_amdgcn_mfma_f32_16x16x32_bf16(onesf, pa0, acc[4], 0, 0, 0);
            #pragma unroll
            for (int dt = 0; dt < 4; ++dt)
                acc[dt] = __builtin_amdgcn_mfma_f32_16x16x32_bf16(vfp[dt][1], pa1, acc[dt], 0, 0, 0);
            acc[4] = __builtin_amdgcn_mfma_f32_16x16x32_bf16(onesf, pa1, acc[4], 0, 0, 0);
            __builtin_amdgcn_s_setprio(0);
        };

        // prefetch masks for tile 0 (consumed when it=1 processes mi=0)
        mmA0 = *(const s16x8*)(mbase + 0);
        mmA1 = *(const s16x8*)(mbase + 32);

        #pragma unroll
        for (int it = 0; it < NKT; ++it) {
            const int cur = it & 1;
            __syncthreads();
            if (it + 1 < NKT) stage(cur ^ 1, it + 1);

            // P(it-1) reads first (shortest lgkm wait for PV below)
            s16x8 pr0, pr1;
            if (it > 0) {
                const unsigned short* Pr = &Pb2[cur ^ 1][0];
                pr0 = *(const s16x8*)&Pr[lq * 64 + ((grp ^ (lq & 7)) * 8)];
                pr1 = *(const s16x8*)&Pr[lq * 64 + (((4 + grp) ^ (lq & 7)) * 8)];
            }
            // V(it) fragment reads (consumed next iteration)
            s16x8 vfc[4][2];
            #pragma unroll
            for (int dt = 0; dt < 4; ++dt)
                #pragma unroll
                for (int kh = 0; kh < 2; ++kh)
                    vfc[dt][kh] = *(const s16x8*)&KVl[cur][1][((dt * 2 + kh) << 9) + l * 8];
            // mask prefetch for tile it (consumed next iteration as mi=it)
            s16x8 mmB0 = *(const s16x8*)(mbase + it * 64);
            s16x8 mmB1 = *(const s16x8*)(mbase + it * 64 + 32);

            if (it > 0) pv(pr0, pr1, mmA0, mmA1);

            #pragma unroll
            for (int dt = 0; dt < 4; ++dt) {
                vfp[dt][0] = vfc[dt][0];
                vfp[dt][1] = vfc[dt][1];
            }
            mmA0 = mmB0; mmA1 = mmB1;
        }
        __syncthreads();      // P(NKT-1) visible
        {
            const unsigned short* Pr = &Pb2[(NKT - 1) & 1][0];
            s16x8 pr0 = *(const s16x8*)&Pr[lq * 64 + ((grp ^ (lq & 7)) * 8)];
            s16x8 pr1 = *(const s16x8*)&Pr[lq * 64 + (((4 + grp) ^ (lq & 7)) * 8)];
            pv(pr0, pr1, mmA0, mmA1);
        }

        const int q = q0 + lq;
        if (q < S) {
            const float inv = 1.0f / acc[4][0];
            float* bp = ((vv == 0)
                ? out_h    + (size_t)(b * S + q) * D
                : out_newh + (size_t)((b * NM + vv - 1) * S + q) * D) + hh * 64 + grp * 4;
            #pragma unroll
            for (int dt = 0; dt < 4; ++dt) {
                float4 s4;
                s4.x = acc[dt][0] * inv; s4.y = acc[dt][1] * inv;
                s4.z = acc[dt][2] * inv; s4.w = acc[dt][3] * inv;
                *(float4*)(bp + dt * 16) = s4;
            }
        }
    }
}

// ---------------------------------------------------------------------------
extern "C" void kernel_launch(void* const* d_in, const int* in_sizes, int n_in,
                              void* d_out, int out_size, void* d_ws, size_t ws_size,
                              hipStream_t stream)
{
    const float* x     = (const float*)d_in[0];
    const int*   masks = (const int*)  d_in[1];
    const float* Wq    = (const float*)d_in[2];
    const float* bq    = (const float*)d_in[3];
    const float* Wk    = (const float*)d_in[4];
    const float* bk    = (const float*)d_in[5];
    const float* Wv    = (const float*)d_in[6];
    const float* bv    = (const float*)d_in[7];

    float* out = (float*)d_out;
    float* out_h    = out;
    float* out_newh = out + OUT_NEWH_OFF;
    float* out_idx  = out + OUT_IDX_OFF;
    float* out_newx = out + OUT_NEWX_OFF;

    unsigned short* Qf  = (unsigned short*)d_ws;
    unsigned short* Kf  = Qf + QF_SZ;
    unsigned short* Vf  = Kf + KF_SZ;
    unsigned short* Mmb = Vf + VF_SZ;      // B*5*KPAD

    // bf16 scratch aliased into the START of out_newh (6.7MB of 25MB):
    // consumed by qkv, then fully overwritten by the attention launch.
    // This frees out_newx so the copy can run concurrently with qkv.
    unsigned short* xb = (unsigned short*)out_newh;
    unsigned short* Wb = xb + BSD;

    conv_kernel<<<1634, 256, 0, stream>>>(x, Wq, Wk, Wv, masks, xb, Wb, Mmb,
                                          Qf, Kf, Vf);
    qkv_mfma_kernel<<<NQKV + NCPY, 256, 0, stream>>>(xb, Wb, bq, bk, bv,
                                                     Qf, Kf, Vf,
                                                     x, out_newx, out_idx);
    attn_mfma_kernel<<<NATT, 384, 0, stream>>>(Qf, Kf, Vf, Mmb,
                                               out_h, out_newh);
}

// Round 19
// 82.767 us; speedup vs baseline: 1.6318x; 1.0062x over previous
//
#include <hip/hip_runtime.h>

typedef float f32x4 __attribute__((ext_vector_type(4)));
typedef short s16x8 __attribute__((ext_vector_type(8)));

constexpr int B  = 2;
constexpr int S  = 1025;
constexpr int D  = 768;
constexpr int DD = D * D;
constexpr int H  = 12;
constexpr int NM = 4;
constexpr int ROWS = B * S;              // 2050
constexpr int BSD  = B * S * D;          // 1,574,400
constexpr int KPAD = 1088;               // padded key dim for mask table
constexpr int NHB  = B * H;              // 24
constexpr int NQT  = 65;                 // q-tiles of 16
constexpr int NKT  = 17;                 // key-tiles of 64
constexpr int NV5  = 5;                  // softmax variants (base + 4 masks)
constexpr int NATT = NHB * NQT;          // 1560 attention blocks (= 8 x 195)
constexpr int NQKV = 33 * 18;            // 594 qkv blocks (64x128 tiles)
constexpr int NCPY = 512;                // copy blocks appended to qkv grid
constexpr int OUT_NEWH_OFF = BSD;
constexpr int OUT_IDX_OFF  = BSD + NM * BSD;
constexpr int OUT_NEWX_OFF = OUT_IDX_OFF + B * NM;

// fold 1/sqrt(64) * log2(e) into Q so attention uses raw v_exp_f32 (2^x)
#define QSCALE 0.18033688011112042f

// fragment array sizes (u16 elements)
constexpr size_t QF_SZ = (size_t)NHB * NQT * 2 * 512;        // 1,597,440
constexpr size_t KF_SZ = (size_t)NHB * NKT * 4 * 2 * 512;    // 1,671,168
constexpr size_t VF_SZ = KF_SZ;

__device__ __forceinline__ unsigned short f2bf(float f) {
    unsigned u = __builtin_bit_cast(unsigned, f);
    u += 0x7FFF + ((u >> 16) & 1);          // RTNE
    return (unsigned short)(u >> 16);
}

__device__ __forceinline__ void gll16(const void* g, void* l) {
    __builtin_amdgcn_global_load_lds(
        (const __attribute__((address_space(1))) void*)g,
        (__attribute__((address_space(3))) void*)l, 16, 0, 0);
}

// ---------------------------------------------------------------------------
// Kernel 0: convert x, Wq/Wk/Wv to bf16; build 5-variant bf16 mask bitmask
// table; zero the PAD fragment tiles of Qf/Kf/Vf.
// xb/Wb live at the START of the out_newh region of d_out (6.7MB of 25MB) —
// consumed by qkv, then fully overwritten by the attention launch.
// ---------------------------------------------------------------------------
__global__ __launch_bounds__(256) void conv_kernel(
    const float* __restrict__ x, const float* __restrict__ Wq,
    const float* __restrict__ Wk, const float* __restrict__ Wv,
    const int* __restrict__ masks,
    unsigned short* __restrict__ xb, unsigned short* __restrict__ Wb,
    unsigned short* __restrict__ Mmb,
    unsigned short* __restrict__ Qf, unsigned short* __restrict__ Kf,
    unsigned short* __restrict__ Vf)
{
    constexpr int NX8 = BSD / 8;        // 196800
    constexpr int NW8 = DD / 8;         // 73728
    constexpr int TOT = NX8 + 3 * NW8;  // 417984
    const int stride = gridDim.x * 256;
    const int tid = blockIdx.x * 256 + threadIdx.x;
    for (int c = tid; c < TOT; c += stride) {
        const float* src;
        unsigned short* dst;
        if (c < NX8) { src = x + (size_t)c * 8; dst = xb + (size_t)c * 8; }
        else {
            const int cc = c - NX8;
            const int mt = cc / NW8;
            const int rr = cc - mt * NW8;
            src = ((mt == 0) ? Wq : (mt == 1) ? Wk : Wv) + (size_t)rr * 8;
            dst = Wb + (size_t)mt * DD + (size_t)rr * 8;
        }
        const float4 a = *(const float4*)src;
        const float4 b2 = *(const float4*)(src + 4);
        s16x8 v;
        v[0] = (short)f2bf(a.x);  v[1] = (short)f2bf(a.y);
        v[2] = (short)f2bf(a.z);  v[3] = (short)f2bf(a.w);
        v[4] = (short)f2bf(b2.x); v[5] = (short)f2bf(b2.y);
        v[6] = (short)f2bf(b2.z); v[7] = (short)f2bf(b2.w);
        *(s16x8*)dst = v;
    }
    // mask bitmask table: Mmb[b][vv][KPAD]; vv=0 keeps all real keys
    if (tid < B * NV5 * KPAD) {            // 10880
        const int k    = tid % KPAD;
        const int rest = tid / KPAD;
        const int vv   = rest % NV5;
        const int bb   = rest / NV5;
        unsigned short m;
        if (vv == 0) m = (k < S) ? 0xFFFFu : 0u;
        else m = (k >= 1 && k < S &&
                  masks[(size_t)(bb * NM + vv - 1) * (S - 1) + k - 1]) ? 0xFFFFu : 0u;
        Mmb[tid] = m;
    }
    // zero pad fragment tiles (qkv_mfma writes the valid entries afterwards)
    constexpr int KZ = NHB * 8 * 512;      // 98304 (last key tile: rows 1024..1087)
    for (int i = tid; i < KZ; i += stride) {
        const int hb = i >> 12, off = i & 4095;
        Kf[(((size_t)(hb * NKT + NKT - 1)) << 12) + off] = 0;
        Vf[(((size_t)(hb * NKT + NKT - 1)) << 12) + off] = 0;
    }
    constexpr int QZ = NHB * 2 * 512;      // 24576 (last q tile: rows 1024..1039)
    for (int i = tid; i < QZ; i += stride) {
        const int hb = i >> 10, off = i & 1023;
        Qf[(((size_t)(hb * NQT + NQT - 1) * 2) << 9) + off] = 0;
    }
}

// ---------------------------------------------------------------------------
// Kernel 1: QKV projection, 64x128-tile bf16 MFMA GEMM over the concatenated
// weight matrix [2304][768] (cy 0-5 = Q, 6-11 = K, 12-17 = V cols), grid
// flattened 1D: blocks < NQKV do GEMM; blocks >= NQKV do the new_x copy +
// img_idx (independent work filling CUs idle during qkv imbalance).
// Epilogue scatters to MFMA FRAGMENT ORDER (unchanged).
// ---------------------------------------------------------------------------
__global__ __launch_bounds__(256, 2) void qkv_mfma_kernel(
    const unsigned short* __restrict__ xb, const unsigned short* __restrict__ Wb,
    const float* __restrict__ bq, const float* __restrict__ bk,
    const float* __restrict__ bv,
    unsigned short* __restrict__ Qf, unsigned short* __restrict__ Kf,
    unsigned short* __restrict__ Vf,
    const float* __restrict__ x,
    float* __restrict__ out_newx, float* __restrict__ out_idx)
{
    if (blockIdx.x >= NQKV) {
        // ---- fused: new_x broadcast copy + img_idx ----
        const int cb = blockIdx.x - NQKV;
        const int SLAB4  = S * D / 4;
        const int TOTAL4 = B * NM * SLAB4;
        const float4* x4 = (const float4*)x;
        float4* o4 = (float4*)out_newx;
        for (int f = cb * 256 + threadIdx.x; f < TOTAL4; f += NCPY * 256) {
            const int bm  = f / SLAB4;
            const int rem = f - bm * SLAB4;
            o4[f] = x4[(bm >> 2) * SLAB4 + rem];
        }
        if (cb == 0 && threadIdx.x < B * NM)
            out_idx[threadIdx.x] = (float)(threadIdx.x >> 2);
        return;
    }

    __shared__ __align__(16) unsigned short Xs[2][64 * 64];    // 16KB
    __shared__ __align__(16) unsigned short Wl[2][128 * 64];   // 32KB

    const int t = threadIdx.x;
    const int bx = blockIdx.x % 33;
    const int cy = blockIdx.x / 33;      // 0..17
    const int row0 = bx * 64;
    const int mt = cy / 6;
    const int col0 = (cy % 6) * 128;     // within-matrix column base
    const float* bias = (mt == 0) ? bq : (mt == 1) ? bk : bv;
    const unsigned short* Wsrc = Wb + (size_t)mt * DD;

    const int w = t >> 6, l = t & 63, lq = l & 15, grp = l >> 4;

    auto stage = [&](int buf, int k0) {
        #pragma unroll
        for (int i = 0; i < 2; ++i) {               // X: 512 chunks
            const int slot = i * 256 + t;
            const int r = slot >> 3, cl = slot & 7;
            const int cg = cl ^ (r & 7);
            int row = row0 + r; if (row > ROWS - 1) row = ROWS - 1;
            gll16(xb + (size_t)row * D + k0 + cg * 8, &Xs[buf][slot * 8]);
        }
        #pragma unroll
        for (int i = 0; i < 4; ++i) {               // W: 1024 chunks
            const int slot = i * 256 + t;
            const int r = slot >> 3, cl = slot & 7;
            const int cg = cl ^ (r & 7);
            gll16(Wsrc + (size_t)(col0 + r) * D + k0 + cg * 8, &Wl[buf][slot * 8]);
        }
    };

    f32x4 acc[4][2] = {};
    stage(0, 0);

    for (int ks = 0; ks < 12; ++ks) {
        const int cur = ks & 1;
        __syncthreads();
        if (ks + 1 < 12) stage(cur ^ 1, (ks + 1) * 64);

        s16x8 a[4][2], bf[2][2];
        #pragma unroll
        for (int i = 0; i < 4; ++i) {
            const int xr = i * 16 + lq;
            #pragma unroll
            for (int kh = 0; kh < 2; ++kh)
                a[i][kh] = *(const s16x8*)&Xs[cur][xr * 64 + (((kh * 4 + grp) ^ (xr & 7)) * 8)];
        }
        #pragma unroll
        for (int j = 0; j < 2; ++j) {
            const int wrow = w * 32 + j * 16 + lq;
            #pragma unroll
            for (int kh = 0; kh < 2; ++kh)
                bf[j][kh] = *(const s16x8*)&Wl[cur][wrow * 64 + (((kh * 4 + grp) ^ (wrow & 7)) * 8)];
        }
        #pragma unroll
        for (int i = 0; i < 4; ++i)
            #pragma unroll
            for (int j = 0; j < 2; ++j) {
                acc[i][j] = __builtin_amdgcn_mfma_f32_16x16x32_bf16(a[i][0], bf[j][0], acc[i][j], 0, 0, 0);
                acc[i][j] = __builtin_amdgcn_mfma_f32_16x16x32_bf16(a[i][1], bf[j][1], acc[i][j], 0, 0, 0);
            }
    }

    // epilogue: bias add + fragment-order scatter (bf16)
    #pragma unroll
    for (int j = 0; j < 2; ++j) {
        const int col = col0 + w * 32 + j * 16 + lq;    // 0..767 within matrix
        const float bv_ = bias[col];
        #pragma unroll
        for (int i = 0; i < 4; ++i) {
            #pragma unroll
            for (int r = 0; r < 4; ++r) {
                const int row = row0 + i * 16 + grp * 4 + r;
                if (row >= ROWS) continue;
                const float raw = acc[i][j][r] + bv_;
                const int bb = (row >= S) ? 1 : 0;
                const int s  = row - bb * S;
                const int hb2 = bb * H + (col >> 6);
                const int d   = col & 63;
                if (mt == 0) {
                    const size_t idx = (((size_t)(hb2 * NQT + (s >> 4)) * 2 + (d >> 5)) << 9)
                                     + (((((d >> 3) & 3) << 4) + (s & 15)) << 3) + (d & 7);
                    Qf[idx] = f2bf(raw * QSCALE);
                } else if (mt == 1) {
                    const size_t idx = ((((size_t)(hb2 * NKT + (s >> 6)) * 4 + ((s >> 4) & 3)) * 2 + (d >> 5)) << 9)
                                     + (((((d >> 3) & 3) << 4) + (s & 15)) << 3) + (d & 7);
                    Kf[idx] = f2bf(raw);
                } else {
                    const int kk = s & 63;
                    const size_t idx = ((((size_t)(hb2 * NKT + (s >> 6)) * 4 + (d >> 4)) * 2 + (kk >> 5)) << 9)
                                     + (((((kk >> 3) & 3) << 4) + (d & 15)) << 3) + (kk & 7);
                    Vf[idx] = f2bf(raw);
                }
            }
        }
    }
}

// ---------------------------------------------------------------------------
// Kernel 2: MFMA attention, SPLIT-PRODUCER p/c (7 waves = 448 thr):
//   waves 0,1 (producers): wave w handles key sub-tiles kt = {2w, 2w+1}:
//     4 ds_read + 4 QK MFMA + 8 exp + 2 P-writes — producer critical path
//     halved vs the single-producer r10 structure.
//   waves 2..6 (consumers): one softmax variant each (mask prefetch one
//     phase ahead, V prefetch-carried). P chunk ranges per kt are disjoint,
//     so producers never collide; the phase barrier orders the P handoff.
// ---------------------------------------------------------------------------
__global__ __launch_bounds__(448) void attn_mfma_kernel(
    const unsigned short* __restrict__ Qf, const unsigned short* __restrict__ Kf,
    const unsigned short* __restrict__ Vf, const unsigned short* __restrict__ Mmb,
    float* __restrict__ out_h, float* __restrict__ out_newh)
{
    __shared__ __align__(16) unsigned short KVl[2][2][4096];  // [buf][K/V] 32KB
    __shared__ __align__(16) unsigned short Pb2[2][1024];     // shared P, 4KB

    const int orig = blockIdx.x;
    const int wgid = (orig & 7) * 195 + (orig >> 3);   // 1560 = 8 x 195
    const int hb = wgid / NQT;           // 0..23
    const int qt = wgid - hb * NQT;      // 0..64
    const int b  = hb / H, hh = hb - b * H;
    const int q0 = qt * 16;

    const int t = threadIdx.x;
    const int w = t >> 6, l = t & 63;
    const int lq = l & 15, grp = l >> 4;

    const unsigned short* kfT = Kf + (((size_t)(hb * NKT)) << 12);
    const unsigned short* vfT = Vf + (((size_t)(hb * NKT)) << 12);

    // all threads cooperatively stage tile -> LDS buf (flat, lane-linear)
    auto stage = [&](int buf, int tile) {
        const unsigned short* ks = kfT + ((size_t)tile << 12);
        const unsigned short* vs = vfT + ((size_t)tile << 12);
        #pragma unroll
        for (int i = 0; i < 3; ++i) {
            const int s = t + i * 448;
            if (s < 512)       gll16(ks + s * 8, &KVl[buf][0][s * 8]);
            else if (s < 1024) gll16(vs + (s - 512) * 8, &KVl[buf][1][(s - 512) * 8]);
        }
    };

    stage(0, 0);

    if (w < 2) {
        // ========== producer w: key sub-tiles kt = {2w, 2w+1} ==========
        const int ktb = w * 2;
        s16x8 qf0, qf1;
        {
            const unsigned short* p = Qf + (((size_t)(hb * NQT + qt) * 2) << 9) + (l << 3);
            qf0 = *(const s16x8*)p;
            qf1 = *(const s16x8*)(p + 512);
        }
        #pragma unroll
        for (int it = 0; it < NKT; ++it) {
            const int cur = it & 1;
            __syncthreads();
            if (it + 1 < NKT) stage(cur ^ 1, it + 1);

            s16x8 kf[2][2];
            #pragma unroll
            for (int kk = 0; kk < 2; ++kk)
                #pragma unroll
                for (int kh = 0; kh < 2; ++kh)
                    kf[kk][kh] = *(const s16x8*)&KVl[cur][0][(((ktb + kk) * 2 + kh) << 9) + l * 8];

            f32x4 qk[2] = {};
            __builtin_amdgcn_s_setprio(1);
            #pragma unroll
            for (int kk = 0; kk < 2; ++kk) {
                qk[kk] = __builtin_amdgcn_mfma_f32_16x16x32_bf16(kf[kk][0], qf0, qk[kk], 0, 0, 0);
                qk[kk] = __builtin_amdgcn_mfma_f32_16x16x32_bf16(kf[kk][1], qf1, qk[kk], 0, 0, 0);
            }
            __builtin_amdgcn_s_setprio(0);

            unsigned short* P = &Pb2[cur][0];
            #pragma unroll
            for (int kk = 0; kk < 2; ++kk) {
                const int kt = ktb + kk;
                float e0, e1, e2, e3;
                asm("v_exp_f32 %0, %1" : "=v"(e0) : "v"(qk[kk][0]));
                asm("v_exp_f32 %0, %1" : "=v"(e1) : "v"(qk[kk][1]));
                asm("v_exp_f32 %0, %1" : "=v"(e2) : "v"(qk[kk][2]));
                asm("v_exp_f32 %0, %1" : "=v"(e3) : "v"(qk[kk][3]));
                unsigned d0, d1;
                asm("v_cvt_pk_bf16_f32 %0, %1, %2" : "=v"(d0) : "v"(e0), "v"(e1));
                asm("v_cvt_pk_bf16_f32 %0, %1, %2" : "=v"(d1) : "v"(e2), "v"(e3));
                const int chunk = kt * 2 + (grp >> 1);
                *(uint2*)&P[lq * 64 + ((chunk ^ (lq & 7)) * 8) + (grp & 1) * 4] =
                    make_uint2(d0, d1);
            }
        }
        __syncthreads();      // expose P(NKT-1) to consumers
    } else {
        // ================= consumer: one variant's PV =================
        const int vv = w - 2;                               // 0..4
        const unsigned short* mbase = Mmb + (size_t)(b * NV5 + vv) * KPAD + grp * 8;

        s16x8 onesf;
        #pragma unroll
        for (int i = 0; i < 8; ++i) onesf[i] = (short)0x3F80;   // bf16 1.0

        f32x4 acc[5] = {};    // dt 0..3 = O^T tiles, 4 = sums
        s16x8 vfp[4][2];
        s16x8 mmA0, mmA1;     // masks for tile it-1 (prefetched last phase)

        auto pv = [&](s16x8 ea0, s16x8 ea1, s16x8 mm0, s16x8 mm1) {
            s16x8 pa0 = ea0 & mm0;
            s16x8 pa1 = ea1 & mm1;
            __builtin_amdgcn_s_setprio(1);
            #pragma unroll
            for (int dt = 0; dt < 4; ++dt)
                acc[dt] = __builtin_amdgcn_mfma_f32_16x16x32_bf16(vfp[dt][0], pa0, acc[dt], 0, 0, 0);
            acc[4] = __builtin_amdgcn_mfma_f32_16x16x32_bf16(onesf, pa0, acc[4], 0, 0, 0);
            #pragma unroll
            for (int dt = 0; dt < 4; ++dt)
                acc[dt] = __builtin_amdgcn_mfma_f32_16x16x32_bf16(vfp[dt][1], pa1, acc[dt], 0, 0, 0);
            acc[4] = __builtin_amdgcn_mfma_f32_16x16x32_bf16(onesf, pa1, acc[4], 0, 0, 0);
            __builtin_amdgcn_s_setprio(0);
        };

        // prefetch masks for tile 0 (consumed when it=1 processes mi=0)
        mmA0 = *(const s16x8*)(mbase + 0);
        mmA1 = *(const s16x8*)(mbase + 32);

        #pragma unroll
        for (int it = 0; it < NKT; ++it) {
            const int cur = it & 1;
            __syncthreads();
            if (it + 1 < NKT) stage(cur ^ 1, it + 1);

            // P(it-1) reads first (shortest lgkm wait for PV below)
            s16x8 pr0, pr1;
            if (it > 0) {
                const unsigned short* Pr = &Pb2[cur ^ 1][0];
                pr0 = *(const s16x8*)&Pr[lq * 64 + ((grp ^ (lq & 7)) * 8)];
                pr1 = *(const s16x8*)&Pr[lq * 64 + (((4 + grp) ^ (lq & 7)) * 8)];
            }
            // V(it) fragment reads (consumed next iteration)
            s16x8 vfc[4][2];
            #pragma unroll
            for (int dt = 0; dt < 4; ++dt)
                #pragma unroll
                for (int kh = 0; kh < 2; ++kh)
                    vfc[dt][kh] = *(const s16x8*)&KVl[cur][1][((dt * 2 + kh) << 9) + l * 8];
            // mask prefetch for tile it (consumed next iteration as mi=it)
            s16x8 mmB0 = *(const s16x8*)(mbase + it * 64);
            s16x8 mmB1 = *(const s16x8*)(mbase + it * 64 + 32);

            if (it > 0) pv(pr0, pr1, mmA0, mmA1);

            #pragma unroll
            for (int dt = 0; dt < 4; ++dt) {
                vfp[dt][0] = vfc[dt][0];
                vfp[dt][1] = vfc[dt][1];
            }
            mmA0 = mmB0; mmA1 = mmB1;
        }
        __syncthreads();      // P(NKT-1) visible
        {
            const unsigned short* Pr = &Pb2[(NKT - 1) & 1][0];
            s16x8 pr0 = *(const s16x8*)&Pr[lq * 64 + ((grp ^ (lq & 7)) * 8)];
            s16x8 pr1 = *(const s16x8*)&Pr[lq * 64 + (((4 + grp) ^ (lq & 7)) * 8)];
            pv(pr0, pr1, mmA0, mmA1);
        }

        const int q = q0 + lq;
        if (q < S) {
            const float inv = 1.0f / acc[4][0];
            float* bp = ((vv == 0)
                ? out_h    + (size_t)(b * S + q) * D
                : out_newh + (size_t)((b * NM + vv - 1) * S + q) * D) + hh * 64 + grp * 4;
            #pragma unroll
            for (int dt = 0; dt < 4; ++dt) {
                float4 s4;
                s4.x = acc[dt][0] * inv; s4.y = acc[dt][1] * inv;
                s4.z = acc[dt][2] * inv; s4.w = acc[dt][3] * inv;
                *(float4*)(bp + dt * 16) = s4;
            }
        }
    }
}

// ---------------------------------------------------------------------------
extern "C" void kernel_launch(void* const* d_in, const int* in_sizes, int n_in,
                              void* d_out, int out_size, void* d_ws, size_t ws_size,
                              hipStream_t stream)
{
    const float* x     = (const float*)d_in[0];
    const int*   masks = (const int*)  d_in[1];
    const float* Wq    = (const float*)d_in[2];
    const float* bq    = (const float*)d_in[3];
    const float* Wk    = (const float*)d_in[4];
    const float* bk    = (const float*)d_in[5];
    const float* Wv    = (const float*)d_in[6];
    const float* bv    = (const float*)d_in[7];

    float* out = (float*)d_out;
    float* out_h    = out;
    float* out_newh = out + OUT_NEWH_OFF;
    float* out_idx  = out + OUT_IDX_OFF;
    float* out_newx = out + OUT_NEWX_OFF;

    unsigned short* Qf  = (unsigned short*)d_ws;
    unsigned short* Kf  = Qf + QF_SZ;
    unsigned short* Vf  = Kf + KF_SZ;
    unsigned short* Mmb = Vf + VF_SZ;      // B*5*KPAD

    // bf16 scratch aliased into the START of out_newh (6.7MB of 25MB):
    // consumed by qkv, then fully overwritten by the attention launch.
    unsigned short* xb = (unsigned short*)out_newh;
    unsigned short* Wb = xb + BSD;

    conv_kernel<<<1634, 256, 0, stream>>>(x, Wq, Wk, Wv, masks, xb, Wb, Mmb,
                                          Qf, Kf, Vf);
    qkv_mfma_kernel<<<NQKV + NCPY, 256, 0, stream>>>(xb, Wb, bq, bk, bv,
                                                     Qf, Kf, Vf,
                                                     x, out_newx, out_idx);
    attn_mfma_kernel<<<NATT, 448, 0, stream>>>(Qf, Kf, Vf, Mmb,
                                               out_h, out_newh);
}